// Round 7
// baseline (1337.828 us; speedup 1.0000x reference)
//
#include <hip/hip_runtime.h>
#include <math.h>

#define NTOK 16384
#define HDIM 2048
#define NEXP 64
#define TOPK 6
#define TB   32          // tokens per block (4 waves x 8 tokens)
#define CH   64          // h per chunk
#define NCH  (HDIM / CH) // 32 chunks
#define TW   8           // tokens per wave

// wt[buf][slot][lane]: W chunk transposed, staged direct-to-LDS.
// Compute read wt[cb][s][lane] = 64 lanes x distinct 16B = full-width b128.
union SMem {
    float4 wt[2][16][NEXP];    // 32 KB
    float  lg[TB][NEXP + 1];   // overlay after final barrier
};

__device__ __forceinline__ void gload_lds16(const float* g, void* l) {
    __builtin_amdgcn_global_load_lds(
        (const __attribute__((address_space(1))) unsigned int*)g,
        (__attribute__((address_space(3))) unsigned int*)l, 16, 0, 0);
}

#define FMA4(A, X, W)                      \
    A.x = fmaf(X.x, W.x, A.x);             \
    A.y = fmaf(X.y, W.y, A.y);             \
    A.z = fmaf(X.z, W.z, A.z);             \
    A.w = fmaf(X.w, W.w, A.w);

__global__ __launch_bounds__(256) void moe_gate_kernel(
        const float* __restrict__ x,
        const float* __restrict__ w,
        float* __restrict__ out)
{
    __shared__ SMem sm;

    const int tid   = threadIdx.x;
    const int lane  = tid & 63;      // expert owned by this lane
    const int wv    = tid >> 6;      // token group: tokens TW*wv .. TW*wv+7
    const int tbase = blockIdx.x * TB;

    // x base for this wave's 8 tokens. Pin to VGPR via opaque asm: prevents
    // the compiler scalarizing the (wave-uniform) broadcast loads into
    // s_load -- the lgkmcnt-collision disease that killed R5/R6.
    const float* xf = x + (size_t)(tbase + TW * wv) * HDIM;
    asm volatile("" : "+v"(xf));
    const char* xb = (const char*)xf;

    // acc[t]: float4 j-partials (j = h%4, strictly ascending h) for
    // (token TW*wv+t, expert lane). Bit-identical accumulation to R1.
    float4 acc[TW];
    #pragma unroll
    for (int t = 0; t < TW; ++t) acc[t] = make_float4(0.f, 0.f, 0.f, 0.f);

    // ---- prologue: stage W chunk 0 (transposed, direct-to-LDS); x step 0 ----
    #pragma unroll
    for (int k = 0; k < 4; ++k) {
        const int slot = 4 * wv + k;
        gload_lds16(w + (size_t)lane * HDIM + 4 * slot, &sm.wt[0][slot][0]);
    }
    float4 xA[TW], xB[TW];
    #pragma unroll
    for (int t = 0; t < TW; ++t)
        xA[t] = *(const float4*)(xb + (size_t)t * (HDIM * 4));
    __syncthreads();   // each wave drains its own vmcnt before barrier -> staged

    for (int c = 0; c < NCH; ++c) {
        const int cb = c & 1;

        // stage next W chunk into the other buffer (readers of that buffer
        // finished before the barrier that started this chunk)
        if (c + 1 < NCH) {
            #pragma unroll
            for (int k = 0; k < 4; ++k) {
                const int slot = 4 * wv + k;
                gload_lds16(w + (size_t)lane * HDIM + (size_t)(c + 1) * CH + 4 * slot,
                            &sm.wt[cb ^ 1][slot][0]);
            }
        }

        const char* xc = xb + (size_t)c * (CH * 4);

        // 16 steps x (1 full-width ds_read_b128 + 8 broadcast x-loads + 32 v_fma)
        #pragma unroll
        for (int s = 0; s < 16; ++s) {
            // prefetch next step's x into the other buffer (vmcnt path)
            if (s < 15) {
                if (s & 1) {
                    #pragma unroll
                    for (int t = 0; t < TW; ++t)
                        xA[t] = *(const float4*)(xc + (size_t)t * (HDIM * 4) + 16 * (s + 1));
                } else {
                    #pragma unroll
                    for (int t = 0; t < TW; ++t)
                        xB[t] = *(const float4*)(xc + (size_t)t * (HDIM * 4) + 16 * (s + 1));
                }
            } else if (c + 1 < NCH) {
                // s==15 is odd: next chunk's step 0 goes into xA (parity holds)
                #pragma unroll
                for (int t = 0; t < TW; ++t)
                    xA[t] = *(const float4*)(xc + (size_t)t * (HDIM * 4) + CH * 4);
            }

            const float4 wq = sm.wt[cb][s][lane];   // ds_read_b128, conflict-free

            if (s & 1) {
                #pragma unroll
                for (int t = 0; t < TW; ++t) { FMA4(acc[t], xB[t], wq) }
            } else {
                #pragma unroll
                for (int t = 0; t < TW; ++t) { FMA4(acc[t], xA[t], wq) }
            }
        }
        __syncthreads();
    }

    // ---- logits: np SSE combine (J0+J2)+(J1+J3); zero seams ----
    #pragma unroll
    for (int t = 0; t < TW; ++t)
        sm.lg[TW * wv + t][lane] =
            (acc[t].x + acc[t].z) + (acc[t].y + acc[t].w);
    __syncthreads();

    // ---- per-token top-6 + softmax + renorm (identical numerics to R1) ----
    if (tid < TB) {
        float val[TOPK];
        int   idx[TOPK];
        #pragma unroll
        for (int k = 0; k < TOPK; ++k) { val[k] = -3.0e38f; idx[k] = 0; }

        for (int e = 0; e < NEXP; ++e) {
            float cv = sm.lg[tid][e];
            int   ci = e;
            #pragma unroll
            for (int k = 0; k < TOPK; ++k) {
                if (cv > val[k]) {                 // strict >: lowest index wins ties
                    const float tv = val[k]; const int ti = idx[k];
                    val[k] = cv; idx[k] = ci;
                    cv = tv; ci = ti;
                }
            }
        }

        const float m = val[0];
        float ex[TOPK];
        float s = 0.f;
        #pragma unroll
        for (int k = 0; k < TOPK; ++k) { ex[k] = expf(val[k] - m); s += ex[k]; }
        float p[TOPK];
        float d = 0.f;
        #pragma unroll
        for (int k = 0; k < TOPK; ++k) { p[k] = ex[k] / s; d += p[k]; }
        d += 1e-20f;

        const int tg = tbase + tid;
        float* oi = out;                           // idx chunk   [NTOK*TOPK]
        float* ow = out + (size_t)NTOK * TOPK;     // weight chunk
        #pragma unroll
        for (int k = 0; k < TOPK; ++k) {
            oi[tg * TOPK + k] = (float)idx[k];
            ow[tg * TOPK + k] = p[k] / d;
        }
    }
}

extern "C" void kernel_launch(void* const* d_in, const int* in_sizes, int n_in,
                              void* d_out, int out_size, void* d_ws, size_t ws_size,
                              hipStream_t stream) {
    const float* x = (const float*)d_in[0];
    const float* w = (const float*)d_in[1];
    float* out = (float*)d_out;
    dim3 grid(NTOK / TB);   // 512 blocks -> 2 blocks/CU, 8 waves/CU
    dim3 block(256);        // 4 waves; lane = expert, wave = 8 tokens
    hipLaunchKernelGGL(moe_gate_kernel, grid, block, 0, stream, x, w, out);
}

// Round 9
// 207.285 us; speedup vs baseline: 6.4541x; 6.4541x over previous
//
#include <hip/hip_runtime.h>
#include <math.h>

#define NTOK 16384
#define HDIM 2048
#define NEXP 64
#define TOPK 6
#define TB   16          // tokens per block
#define CH   64          // h per chunk (16 float4 slots, 256 BYTES per row)
#define NCH  (HDIM / CH) // 32 chunks
#define CHB  256         // chunk stride in bytes (CH * 4) -- R8 bug was 1024 here

// LDS: double-buffered W chunk (float4-slot XOR-swizzled), unioned with
// epilogue combine buffers. x never touches LDS (VMEM path only).
union SMem {
    float ws[2][NEXP][CH];        // 32 KB: [buf][expert][slot'], slot' = s ^ ((e>>2)&7)
    struct {
        float4 cmb[TB][16][4];    // 16 KB: hh=1 partials [tok][eg][s]
        float  lg[TB][NEXP + 1];  // 4.2 KB logits
    } e;
};

__device__ __forceinline__ void gload_lds16(const float* g, void* l) {
    __builtin_amdgcn_global_load_lds(
        (const __attribute__((address_space(1))) unsigned int*)g,
        (__attribute__((address_space(3))) unsigned int*)l, 16, 0, 0);
}

#define FMA4(A, X, W)                      \
    A.x = fmaf(X.x, W.x, A.x);             \
    A.y = fmaf(X.y, W.y, A.y);             \
    A.z = fmaf(X.z, W.z, A.z);             \
    A.w = fmaf(X.w, W.w, A.w);

// one 4-h step: 4 swizzled W ds_read_b128 + 16 FMA4 on x-regs
#define STEP(XV, ST)                                                        \
    {                                                                       \
        const int sbyte = (((8 * hh + (ST)) << 4)) ^ kx;                    \
        const float4 w0 = *(const float4*)(wb + sbyte);                     \
        const float4 w1 = *(const float4*)(wb + sbyte + CH * 4);            \
        const float4 w2 = *(const float4*)(wb + sbyte + CH * 8);            \
        const float4 w3 = *(const float4*)(wb + sbyte + CH * 12);           \
        FMA4(acc[0][0], XV[0], w0) FMA4(acc[0][1], XV[0], w1)               \
        FMA4(acc[0][2], XV[0], w2) FMA4(acc[0][3], XV[0], w3)               \
        FMA4(acc[1][0], XV[1], w0) FMA4(acc[1][1], XV[1], w1)               \
        FMA4(acc[1][2], XV[1], w2) FMA4(acc[1][3], XV[1], w3)               \
        FMA4(acc[2][0], XV[2], w0) FMA4(acc[2][1], XV[2], w1)               \
        FMA4(acc[2][2], XV[2], w2) FMA4(acc[2][3], XV[2], w3)               \
        FMA4(acc[3][0], XV[3], w0) FMA4(acc[3][1], XV[3], w1)               \
        FMA4(acc[3][2], XV[3], w2) FMA4(acc[3][3], XV[3], w3)               \
    }

__global__ __launch_bounds__(128) void moe_gate_kernel(
        const float* __restrict__ x,
        const float* __restrict__ w,
        float* __restrict__ out)
{
    __shared__ SMem sm;

    const int tid   = threadIdx.x;
    const int lane  = tid & 63;
    const int hh    = tid >> 6;      // wave = h-half: 0 -> h%64 in [0,32), 1 -> [32,64)
    const int q     = lane >> 4;     // token quad: tokens 4q..4q+3
    const int eg    = lane & 15;     // experts 4eg..4eg+3
    const int kx    = (eg & 7) << 4; // byte XOR key for swizzled W reads (lane-const)
    const int tbase = blockIdx.x * TB;

    // x row pointers (byte), advanced by CHB=256 per chunk; all step offsets
    // small immediates. Addresses vary per-lane via q -> vector VMEM path;
    // 16-lane-same-address coalesces to one request, 128B lines reused
    // across consecutive steps by this wave (L1).
    const char* xq[4];
    #pragma unroll
    for (int r = 0; r < 4; ++r)
        xq[r] = (const char*)(x + (size_t)(tbase + 4 * q + r) * HDIM) + 128 * hh;

    // acc[r][s]: float4 j-partials (j=h%4, ascending h within this wave's
    // h-half) for (token 4q+r, expert 4eg+s). Same split/order as R4 (proven).
    float4 acc[4][4];
    #pragma unroll
    for (int r = 0; r < 4; ++r)
        #pragma unroll
        for (int s = 0; s < 4; ++s)
            acc[r][s] = make_float4(0.f, 0.f, 0.f, 0.f);

    float4 xA[4], xB[4];

    // ---- prologue: stage W chunk 0 (pre-swizzled global src -> linear LDS) ----
    #pragma unroll
    for (int k = 0; k < 8; ++k) {
        const int i0 = 128 * k + 64 * hh;          // wave-uniform float4 base
        const int i  = i0 + lane;
        const int e  = i >> 4;
        const int gs = (i & 15) ^ ((e >> 2) & 7);  // inverse swizzle on source
        gload_lds16(w + (size_t)e * HDIM + 4 * gs,
                    (char*)&sm.ws[0][0][0] + 16 * (size_t)i0);
    }
    #pragma unroll
    for (int r = 0; r < 4; ++r)                    // x step 0
        xA[r] = *(const float4*)(xq[r]);
    __syncthreads();                               // drains vmcnt -> all staged

    for (int c = 0; c < NCH; ++c) {
        const int buf = c & 1;
        const char* wb = (const char*)&sm.ws[buf][4 * eg][0];

        // issue st=1's x BEFORE the W gloads so its vmcnt wait doesn't
        // couple to the (slow) staging loads
        #pragma unroll
        for (int r = 0; r < 4; ++r)
            xB[r] = *(const float4*)(xq[r] + 16);

        // stage next W chunk into the other buffer (its readers finished
        // before the barrier that started this chunk)
        if (c + 1 < NCH) {
            #pragma unroll
            for (int k = 0; k < 8; ++k) {
                const int i0 = 128 * k + 64 * hh;
                const int i  = i0 + lane;
                const int e  = i >> 4;
                const int gs = (i & 15) ^ ((e >> 2) & 7);
                gload_lds16(w + (size_t)e * HDIM + (size_t)(c + 1) * CH + 4 * gs,
                            (char*)&sm.ws[buf ^ 1][0][0] + 16 * (size_t)i0);
            }
        }

        STEP(xA, 0)

        // steps 1..7: prefetch next step's x (ping-pong), compute current
        #pragma unroll
        for (int st = 1; st < 8; ++st) {
            if (st < 7) {
                float4* dst = ((st + 1) & 1) ? xB : xA;   // st compile-time: static
                #pragma unroll
                for (int r = 0; r < 4; ++r)
                    dst[r] = *(const float4*)(xq[r] + 16 * (st + 1));
            } else if (c + 1 < NCH) {
                #pragma unroll
                for (int r = 0; r < 4; ++r)        // next chunk's st=0 -> xA
                    xA[r] = *(const float4*)(xq[r] + CHB);
            }
            if (st & 1) STEP(xB, st) else STEP(xA, st)
        }

        #pragma unroll
        for (int r = 0; r < 4; ++r)
            xq[r] += CHB;                           // advance one chunk (256 B)
        __syncthreads();
    }

    // ---- cross-half combine (R4's proven seam): hh=1 stores, hh=0 adds ----
    if (hh == 1) {
        #pragma unroll
        for (int r = 0; r < 4; ++r)
            #pragma unroll
            for (int s = 0; s < 4; ++s)
                sm.e.cmb[4 * q + r][eg][s] = acc[r][s];
    }
    __syncthreads();
    if (hh == 0) {
        #pragma unroll
        for (int r = 0; r < 4; ++r)
            #pragma unroll
            for (int s = 0; s < 4; ++s) {
                const float4 o  = sm.e.cmb[4 * q + r][eg][s];
                const float  J0 = acc[r][s].x + o.x;
                const float  J1 = acc[r][s].y + o.y;
                const float  J2 = acc[r][s].z + o.z;
                const float  J3 = acc[r][s].w + o.w;
                sm.e.lg[4 * q + r][4 * eg + s] = (J0 + J2) + (J1 + J3);  // np SSE order
            }
    }
    __syncthreads();

    // ---- per-token top-6 + softmax + renorm (identical numerics to R1-R4) ----
    if (tid < TB) {
        float val[TOPK];
        int   idx[TOPK];
        #pragma unroll
        for (int k = 0; k < TOPK; ++k) { val[k] = -3.0e38f; idx[k] = 0; }

        for (int e = 0; e < NEXP; ++e) {
            float cv = sm.e.lg[tid][e];
            int   ci = e;
            #pragma unroll
            for (int k = 0; k < TOPK; ++k) {
                if (cv > val[k]) {                 // strict >: lowest index wins ties
                    const float tv = val[k]; const int ti = idx[k];
                    val[k] = cv; idx[k] = ci;
                    cv = tv; ci = ti;
                }
            }
        }

        const float m = val[0];
        float ex[TOPK];
        float s = 0.f;
        #pragma unroll
        for (int k = 0; k < TOPK; ++k) { ex[k] = expf(val[k] - m); s += ex[k]; }
        float p[TOPK];
        float d = 0.f;
        #pragma unroll
        for (int k = 0; k < TOPK; ++k) { p[k] = ex[k] / s; d += p[k]; }
        d += 1e-20f;

        const int tg = tbase + tid;
        float* oi = out;                           // idx chunk   [NTOK*TOPK]
        float* ow = out + (size_t)NTOK * TOPK;     // weight chunk
        #pragma unroll
        for (int k = 0; k < TOPK; ++k) {
            oi[tg * TOPK + k] = (float)idx[k];
            ow[tg * TOPK + k] = p[k] / d;
        }
    }
}

extern "C" void kernel_launch(void* const* d_in, const int* in_sizes, int n_in,
                              void* d_out, int out_size, void* d_ws, size_t ws_size,
                              hipStream_t stream) {
    const float* x = (const float*)d_in[0];
    const float* w = (const float*)d_in[1];
    float* out = (float*)d_out;
    dim3 grid(NTOK / TB);   // 1024 blocks -> 4 blocks/CU, 8 waves/CU
    dim3 block(128);        // 2 waves = 2 h-halves; lane = (token quad, expert quad)
    hipLaunchKernelGGL(moe_gate_kernel, grid, block, 0, stream, x, w, out);
}

// Round 10
// 156.977 us; speedup vs baseline: 8.5224x; 1.3205x over previous
//
#include <hip/hip_runtime.h>
#include <math.h>

#define NTOK 16384
#define HDIM 2048
#define NEXP 64
#define TOPK 6
#define TB   32          // tokens per block
#define CH   64          // h per chunk (16 float4 slots, 256 B per row)
#define NCH  (HDIM / CH) // 32 chunks

// Double-buffered stage tiles (both staged via global_load_lds with
// pre-swizzled global sources; LDS layout linear). Epilogue overlays.
union SMem {
    struct {
        float ws[2][NEXP][CH];    // 32 KB: [buf][e][slot'], slot' = s ^ ((e>>2)&7)
        float xs[2][TB][CH];      // 16 KB: [buf][t][slot'], slot' = s ^ ((t>>2)&3)
    } s;
    struct {
        float4 cmb[2][16][16][4]; // 32 KB: hh=1 partials [ts][tok16][eg][s]
        float  lg[TB][NEXP + 1];  // 8.3 KB logits
    } e;
};

__device__ __forceinline__ void gload_lds16(const float* g, void* l) {
    __builtin_amdgcn_global_load_lds(
        (const __attribute__((address_space(1))) unsigned int*)g,
        (__attribute__((address_space(3))) unsigned int*)l, 16, 0, 0);
}

// Stage one 64-h chunk: W 16 KB (16 insts) + x 8 KB (8 insts), spread over
// 4 waves. Dest = wave-uniform base + lane*16 (linear); source pre-swizzled.
__device__ __forceinline__ void stage_chunk(const float* __restrict__ x,
                                            const float* __restrict__ w,
                                            float* wsb, float* xsb,
                                            int tbase, int c, int wv, int lane) {
    #pragma unroll
    for (int k = 0; k < 4; ++k) {              // W: this wave's 4 of 16 KB-insts
        const int i0 = 64 * (4 * wv + k);      // wave-uniform float4 base
        const int i  = i0 + lane;
        const int e  = i >> 4;
        const int sl = (i & 15) ^ ((e >> 2) & 7);
        gload_lds16(w + (size_t)e * HDIM + (size_t)c * CH + 4 * sl, wsb + 4 * i0);
    }
    #pragma unroll
    for (int k = 0; k < 2; ++k) {              // x: this wave's 2 of 8 KB-insts
        const int i0 = 64 * (2 * wv + k);
        const int i  = i0 + lane;
        const int t  = i >> 4;
        const int sl = (i & 15) ^ ((t >> 2) & 3);
        gload_lds16(x + (size_t)(tbase + t) * HDIM + (size_t)c * CH + 4 * sl, xsb + 4 * i0);
    }
}

#define FMA4(A, X, W)                      \
    A.x = fmaf(X.x, W.x, A.x);             \
    A.y = fmaf(X.y, W.y, A.y);             \
    A.z = fmaf(X.z, W.z, A.z);             \
    A.w = fmaf(X.w, W.w, A.w);

// one 4-h step: 4 W-reads (16-distinct, 2-way) + 4 x-reads (4-distinct
// broadcast, conflict-free) + 64 fma. All LDS (lgkm) -- no vmcnt waits.
#define STEP(ST)                                                            \
    {                                                                       \
        const int so = ((8 * hh + (ST)) << 4);                              \
        const int wo = so ^ kx;                                             \
        const int xo = so ^ kq;                                             \
        const float4 w0 = *(const float4*)(wb + wo);                        \
        const float4 w1 = *(const float4*)(wb + wo + CH * 4);               \
        const float4 w2 = *(const float4*)(wb + wo + CH * 8);               \
        const float4 w3 = *(const float4*)(wb + wo + CH * 12);              \
        const float4 x0 = *(const float4*)(xb0 + xo);                       \
        const float4 x1 = *(const float4*)(xb0 + 256 + xo);                 \
        const float4 x2 = *(const float4*)(xb0 + 512 + xo);                 \
        const float4 x3 = *(const float4*)(xb0 + 768 + xo);                 \
        FMA4(acc[0][0], x0, w0) FMA4(acc[0][1], x0, w1)                     \
        FMA4(acc[0][2], x0, w2) FMA4(acc[0][3], x0, w3)                     \
        FMA4(acc[1][0], x1, w0) FMA4(acc[1][1], x1, w1)                     \
        FMA4(acc[1][2], x1, w2) FMA4(acc[1][3], x1, w3)                     \
        FMA4(acc[2][0], x2, w0) FMA4(acc[2][1], x2, w1)                     \
        FMA4(acc[2][2], x2, w2) FMA4(acc[2][3], x2, w3)                     \
        FMA4(acc[3][0], x3, w0) FMA4(acc[3][1], x3, w1)                     \
        FMA4(acc[3][2], x3, w2) FMA4(acc[3][3], x3, w3)                     \
    }

__global__ __launch_bounds__(256, 2) void moe_gate_kernel(
        const float* __restrict__ x,
        const float* __restrict__ w,
        float* __restrict__ out)
{
    __shared__ SMem sm;

    const int tid   = threadIdx.x;
    const int wv    = tid >> 6;
    const int lane  = tid & 63;
    const int hh    = wv >> 1;        // h-half: waves 0,1 -> slots [0,8); 2,3 -> [8,16)
    const int ts    = wv & 1;         // token sub-block: tokens 16*ts..16*ts+15
    const int q     = lane >> 4;      // token quad
    const int eg    = lane & 15;      // experts 4eg..4eg+3
    const int kx    = (eg & 7) << 4;  // W byte XOR key (lane-const)
    const int kq    = q << 4;         // x byte XOR key (lane-const)
    const int tbase = blockIdx.x * TB;
    const int tokL  = 16 * ts + 4 * q;

    // acc[r][s]: float4 j-partials (j=h%4, ascending h within this wave's
    // h-half) for (token tokL+r, expert 4eg+s). Identical order to R4.
    float4 acc[4][4];
    #pragma unroll
    for (int r = 0; r < 4; ++r)
        #pragma unroll
        for (int s = 0; s < 4; ++s)
            acc[r][s] = make_float4(0.f, 0.f, 0.f, 0.f);

    // ---- prologue: stage chunk 0 ----
    stage_chunk(x, w, &sm.s.ws[0][0][0], &sm.s.xs[0][0][0], tbase, 0, wv, lane);
    __syncthreads();   // vmcnt(0)+lgkm(0)+barrier: buf0 staged

    for (int c = 0; c < NCH; ++c) {
        const int buf = c & 1;

        // issue next chunk's staging FIRST (vmcnt retires during ~1000cy of
        // compute; the barrier's vmcnt(0) drain is then free). Writes the
        // other buffer, whose readers finished before the last barrier.
        if (c + 1 < NCH)
            stage_chunk(x, w, &sm.s.ws[buf ^ 1][0][0], &sm.s.xs[buf ^ 1][0][0],
                        tbase, c + 1, wv, lane);

        // compute this wave's h-half: pure ds_read + fma
        const char* wb  = (const char*)&sm.s.ws[buf][4 * eg][0];
        const char* xb0 = (const char*)&sm.s.xs[buf][tokL][0];
        STEP(0) STEP(1) STEP(2) STEP(3) STEP(4) STEP(5) STEP(6) STEP(7)

        __syncthreads();   // one barrier per chunk
    }

    // ---- cross-half combine (R4's proven seam): hh=1 stores, hh=0 adds ----
    if (hh == 1) {
        #pragma unroll
        for (int r = 0; r < 4; ++r)
            #pragma unroll
            for (int s = 0; s < 4; ++s)
                sm.e.cmb[ts][4 * q + r][eg][s] = acc[r][s];
    }
    __syncthreads();
    if (hh == 0) {
        #pragma unroll
        for (int r = 0; r < 4; ++r)
            #pragma unroll
            for (int s = 0; s < 4; ++s) {
                const float4 o  = sm.e.cmb[ts][4 * q + r][eg][s];
                const float  J0 = acc[r][s].x + o.x;
                const float  J1 = acc[r][s].y + o.y;
                const float  J2 = acc[r][s].z + o.z;
                const float  J3 = acc[r][s].w + o.w;
                sm.e.lg[tokL + r][4 * eg + s] = (J0 + J2) + (J1 + J3);  // np SSE order
            }
    }
    __syncthreads();

    // ---- per-token top-6 + softmax + renorm (identical numerics to R1-R4) ----
    if (tid < TB) {
        float val[TOPK];
        int   idx[TOPK];
        #pragma unroll
        for (int k = 0; k < TOPK; ++k) { val[k] = -3.0e38f; idx[k] = 0; }

        for (int e = 0; e < NEXP; ++e) {
            float cv = sm.e.lg[tid][e];
            int   ci = e;
            #pragma unroll
            for (int k = 0; k < TOPK; ++k) {
                if (cv > val[k]) {                 // strict >: lowest index wins ties
                    const float tv = val[k]; const int ti = idx[k];
                    val[k] = cv; idx[k] = ci;
                    cv = tv; ci = ti;
                }
            }
        }

        const float m = val[0];
        float ex[TOPK];
        float s = 0.f;
        #pragma unroll
        for (int k = 0; k < TOPK; ++k) { ex[k] = expf(val[k] - m); s += ex[k]; }
        float p[TOPK];
        float d = 0.f;
        #pragma unroll
        for (int k = 0; k < TOPK; ++k) { p[k] = ex[k] / s; d += p[k]; }
        d += 1e-20f;

        const int tg = tbase + tid;
        float* oi = out;                           // idx chunk   [NTOK*TOPK]
        float* ow = out + (size_t)NTOK * TOPK;     // weight chunk
        #pragma unroll
        for (int k = 0; k < TOPK; ++k) {
            oi[tg * TOPK + k] = (float)idx[k];
            ow[tg * TOPK + k] = p[k] / d;
        }
    }
}

extern "C" void kernel_launch(void* const* d_in, const int* in_sizes, int n_in,
                              void* d_out, int out_size, void* d_ws, size_t ws_size,
                              hipStream_t stream) {
    const float* x = (const float*)d_in[0];
    const float* w = (const float*)d_in[1];
    float* out = (float*)d_out;
    dim3 grid(NTOK / TB);   // 512 blocks -> 2 blocks/CU, 8 waves/CU
    dim3 block(256);        // 4 waves: (hh, ts) = (wv>>1, wv&1)
    hipLaunchKernelGGL(moe_gate_kernel, grid, block, 0, stream, x, w, out);
}